// Round 1
// baseline (216.390 us; speedup 1.0000x reference)
//
#include <hip/hip_runtime.h>
#include <hip/hip_bf16.h>
#include <hip/hip_fp8.h>
#include <math.h>

#define N 8192
#define D 512
#define BM 128
#define BK 64
#define NSTRIP 64                       // N / BM
#define S_BLOCKS (NSTRIP * NSTRIP)      // 4096 S tiles
#define TRI (NSTRIP * (NSTRIP + 1) / 2) // 2080
#define G_BLOCKS (2 * TRI)              // 4160 Gram tiles
#define SG_BLOCKS (S_BLOCKS + G_BLOCKS) // 8256 (divisible by 8 -> bijective XCD swizzle)

typedef float f32x16 __attribute__((ext_vector_type(16)));
typedef int i32x4 __attribute__((ext_vector_type(4)));
typedef int i32x8 __attribute__((ext_vector_type(8)));

__device__ inline void gload_lds16(const void* g, void* l) {
  __builtin_amdgcn_global_load_lds(
      (const __attribute__((address_space(1))) void*)g,
      (__attribute__((address_space(3))) void*)l, 16, 0, 0);
}

// ---------------- normalize to fp8 e4m3 + exact fp32 diagonal + zero out ----------------
__global__ __launch_bounds__(256) void norm_kernel(
    const float* __restrict__ z1, const float* __restrict__ z2,
    unsigned char* __restrict__ q1, unsigned char* __restrict__ q2,
    float* __restrict__ diag, float* __restrict__ out) {
  int row = blockIdx.x;
  int t = threadIdx.x;
  if (row == 0 && t == 0) out[0] = 0.0f; // atomic target for combine (stream-ordered)
  const float* a = z1 + (size_t)row * D;
  const float* b = z2 + (size_t)row * D;
  float va[2], vb[2];
  float ss1 = 0.f, ss2 = 0.f, dd = 0.f;
#pragma unroll
  for (int i = 0; i < 2; i++) {
    float x = a[t + 256 * i];
    float y = b[t + 256 * i];
    va[i] = x; vb[i] = y;
    ss1 += x * x; ss2 += y * y; dd += x * y;
  }
#pragma unroll
  for (int off = 1; off < 64; off <<= 1) {
    ss1 += __shfl_xor(ss1, off);
    ss2 += __shfl_xor(ss2, off);
    dd  += __shfl_xor(dd,  off);
  }
  __shared__ float red[3][4];
  int wv = t >> 6;
  if ((t & 63) == 0) { red[0][wv] = ss1; red[1][wv] = ss2; red[2][wv] = dd; }
  __syncthreads();
  ss1 = red[0][0] + red[0][1] + red[0][2] + red[0][3];
  ss2 = red[1][0] + red[1][1] + red[1][2] + red[1][3];
  dd  = red[2][0] + red[2][1] + red[2][2] + red[2][3];
  float i1 = 1.0f / fmaxf(sqrtf(ss1), 1e-12f);
  float i2 = 1.0f / fmaxf(sqrtf(ss2), 1e-12f);
#pragma unroll
  for (int i = 0; i < 2; i++) {
    __hip_fp8_e4m3 c1((float)(va[i] * i1)); // OCP e4m3fn
    __hip_fp8_e4m3 c2((float)(vb[i] * i2));
    q1[(size_t)row * D + t + 256 * i] = c1.__x;
    q2[(size_t)row * D + t + 256 * i] = c2.__x;
  }
  if (t == 0) diag[row] = dd * i1 * i2;
}

// ---------------- one 64B-k-chunk staging helper (conflict-spread swizzle) ----------------
__device__ __forceinline__ void stage_tile(
    const unsigned char* __restrict__ P, int base, int k0,
    unsigned char* T, int t) {
#pragma unroll
  for (int it = 0; it < 2; it++) {
    int s = it * 256 + t; // 512 slots of 16B
    int row = s >> 2, cs = s & 3;
    int src = cs ^ ((row >> 1) & 3); // pre-swizzled global source, linear LDS dest
    gload_lds16(P + (size_t)(base + row) * D + k0 + src * 16, &T[s * 16]);
  }
}

// ---------------- 128x128 MX-scaled fp8 MFMA tile (32x32x64, unit scales) --------------
// Same double-buffered pipeline as before: barrier FIRST (drains loads issued one
// full round ago), then issue kc+1's stage into the other buffer, then ds_read+MFMA
// on the current buffer. One barrier/round. Unit E8M0 scales (0x7F = 2^0) make the
// scaled MFMA numerically identical to the non-scaled fp8 MFMA at 2x the pipe rate.
// k-slot <-> lane mapping is arbitrary (A and B agree; sum over k is commutative).
__device__ __forceinline__ void mm_tile_mx(
    const unsigned char* __restrict__ X, const unsigned char* __restrict__ Y,
    int r0, int c0, unsigned char* At0, unsigned char* Bt0,
    unsigned char* At1, unsigned char* Bt1, f32x16 (&acc)[2][2],
    int t, int l31, int kl, int rw, int cw) {
#pragma unroll
  for (int i = 0; i < 2; i++)
#pragma unroll
    for (int j = 0; j < 2; j++)
#pragma unroll
      for (int r = 0; r < 16; r++) acc[i][j][r] = 0.0f;

  // kc-invariant LDS byte offsets: lane reads 32 logical-contiguous k-bytes
  // (chunks 2*kl, 2*kl+1) of its row, through the staging swizzle.
  int offA[2][2], offB[2][2];
#pragma unroll
  for (int i = 0; i < 2; i++) {
    int row = rw * 64 + i * 32 + l31;
    int sw = (row >> 1) & 3;
    offA[i][0] = row * 64 + (((kl << 1) | 0) ^ sw) * 16;
    offA[i][1] = row * 64 + (((kl << 1) | 1) ^ sw) * 16;
  }
#pragma unroll
  for (int j = 0; j < 2; j++) {
    int row = cw * 64 + j * 32 + l31;
    int sw = (row >> 1) & 3;
    offB[j][0] = row * 64 + (((kl << 1) | 0) ^ sw) * 16;
    offB[j][1] = row * 64 + (((kl << 1) | 1) ^ sw) * 16;
  }

  stage_tile(X, r0, 0, At0, t);
  stage_tile(Y, c0, 0, Bt0, t);

#pragma unroll 2
  for (int kc = 0; kc < 8; kc++) {
    unsigned char* Ac = (kc & 1) ? At1 : At0;
    unsigned char* Bc = (kc & 1) ? Bt1 : Bt0;
    unsigned char* An = (kc & 1) ? At0 : At1;
    unsigned char* Bn = (kc & 1) ? Bt0 : Bt1;
    __syncthreads(); // drains vmcnt for Ac/Bc (issued last round); frees An/Bn
    if (kc < 7) {
      stage_tile(X, r0, (kc + 1) * BK, An, t);
      stage_tile(Y, c0, (kc + 1) * BK, Bn, t);
    }
    i32x8 af[2], bf[2];
#pragma unroll
    for (int i = 0; i < 2; i++) {
      i32x4 lo = *(const i32x4*)&Ac[offA[i][0]];
      i32x4 hi = *(const i32x4*)&Ac[offA[i][1]];
      af[i] = __builtin_shufflevector(lo, hi, 0, 1, 2, 3, 4, 5, 6, 7);
    }
#pragma unroll
    for (int j = 0; j < 2; j++) {
      i32x4 lo = *(const i32x4*)&Bc[offB[j][0]];
      i32x4 hi = *(const i32x4*)&Bc[offB[j][1]];
      bf[j] = __builtin_shufflevector(lo, hi, 0, 1, 2, 3, 4, 5, 6, 7);
    }
#pragma unroll
    for (int i = 0; i < 2; i++)
#pragma unroll
      for (int j = 0; j < 2; j++)
        acc[i][j] = __builtin_amdgcn_mfma_scale_f32_32x32x64_f8f6f4(
            af[i], bf[j], acc[i][j], 0 /*cbsz=fp8*/, 0 /*blgp=fp8*/,
            0, 0x7F7F7F7F, 0, 0x7F7F7F7F); // E8M0 0x7F = scale 1.0
  }
}

// ---------------- fused S + G pass: one 128x128 tile per block ----------------
// 32x32 C/D layout: col = lane&31, row = (reg&3) + 8*(reg>>2) + 4*(lane>>5)
__global__ __launch_bounds__(256, 3) void sg_kernel(
    const unsigned char* __restrict__ q1, const unsigned char* __restrict__ q2,
    float* __restrict__ rowS, float* __restrict__ colS,
    float* __restrict__ partG) {
  __shared__ unsigned char At0[BM * BK];
  __shared__ unsigned char Bt0[BM * BK];
  __shared__ unsigned char At1[BM * BK];
  __shared__ unsigned char Bt1[BM * BK];
  __shared__ float redA[2][BM];
  __shared__ float redB[2][BM];

  // bijective XCD-chunked swizzle: each XCD owns a contiguous run of 1032 logical
  // tiles -> row-strip A panels stay L2-resident per XCD (staging BW is co-critical
  // at MX rate).
  int bxr = blockIdx.x;
  int bx = (bxr & 7) * (SG_BLOCKS / 8) + (bxr >> 3);

  int t = threadIdx.x;
  int lane = t & 63;
  int wave = t >> 6;
  int l31 = lane & 31;
  int h = lane >> 5; // k-half for frags / row-half for C/D
  int rw = wave >> 1;
  int cw = wave & 1;
  const float scale = 1.4426950408889634f / 0.04f; // log2(e)/T

  bool smode = bx < S_BLOCKS;
  const unsigned char* X;
  const unsigned char* Y;
  int r0, c0, ga = 0, gb = 0, gg = 0;
  bool diagb = false;
  if (smode) {
    r0 = (bx >> 6) * BM;
    c0 = (bx & 63) * BM;
    X = q1; Y = q2;
  } else {
    int gx = bx - S_BLOCKS;
    gg = (gx >= TRI) ? 1 : 0;
    int tri = gx - gg * TRI;
    int a = (int)((sqrtf(8.0f * (float)tri + 1.0f) - 1.0f) * 0.5f);
    while ((a + 1) * (a + 2) / 2 <= tri) a++;
    while (a * (a + 1) / 2 > tri) a--;
    int b = tri - a * (a + 1) / 2; // b <= a
    ga = a; gb = b;
    X = gg ? q2 : q1; Y = X;
    r0 = a * BM;
    c0 = b * BM;
    diagb = (a == b);
  }

  f32x16 acc[2][2];
  mm_tile_mx(X, Y, r0, c0, At0, Bt0, At1, Bt1, acc, t, l31, h, rw, cw);

  if (smode) {
    // ---- row + col sums of exp2(scale*g); fixed reference (fits fp32) ----
    float csum[2] = {0.0f, 0.0f};
#pragma unroll
    for (int i = 0; i < 2; i++) {
      float rsum[16];
#pragma unroll
      for (int reg = 0; reg < 16; reg++) rsum[reg] = 0.0f;
#pragma unroll
      for (int j = 0; j < 2; j++)
#pragma unroll
        for (int reg = 0; reg < 16; reg++) {
          float e = __builtin_amdgcn_exp2f(acc[i][j][reg] * scale);
          rsum[reg] += e;
          csum[j] += e;
        }
      // row-sum: reduce across the 32 lanes of this k/row-half (bit5 preserved)
#pragma unroll
      for (int reg = 0; reg < 16; reg++) {
#pragma unroll
        for (int off = 1; off < 32; off <<= 1) rsum[reg] += __shfl_xor(rsum[reg], off);
      }
      if (l31 == 0) {
#pragma unroll
        for (int reg = 0; reg < 16; reg++) {
          int rloc = (reg & 3) + 8 * (reg >> 2) + 4 * h;
          redB[cw][rw * 64 + i * 32 + rloc] = rsum[reg];
        }
      }
    }
    // col-sum: add the other row-half, then one lane-half writes
#pragma unroll
    for (int j = 0; j < 2; j++) {
      csum[j] += __shfl_xor(csum[j], 32);
      if (h == 0) redA[rw][cw * 64 + j * 32 + l31] = csum[j];
    }
    __syncthreads();
    if (t < BM) {
      colS[(size_t)(r0 >> 7) * N + c0 + t] = redA[0][t] + redA[1][t];
      rowS[(size_t)(c0 >> 7) * N + r0 + t] = redB[0][t] + redB[1][t];
    }
  } else {
    // ---- Gram: row max (strip a), diag-masked; col max = row max of strip b ----
#pragma unroll
    for (int i = 0; i < 2; i++) {
      float rmax[16];
#pragma unroll
      for (int reg = 0; reg < 16; reg++) {
        int rloc = (reg & 3) + 8 * (reg >> 2) + 4 * h;
        int rr = rw * 64 + i * 32 + rloc;
        float v = -3.0e38f;
#pragma unroll
        for (int j = 0; j < 2; j++) {
          float x = acc[i][j][reg];
          int cc = cw * 64 + j * 32 + l31;
          if (diagb && cc == rr) x = -3.0e38f;
          v = fmaxf(v, x);
        }
        rmax[reg] = v;
      }
#pragma unroll
      for (int reg = 0; reg < 16; reg++) {
#pragma unroll
        for (int off = 1; off < 32; off <<= 1) rmax[reg] = fmaxf(rmax[reg], __shfl_xor(rmax[reg], off));
      }
      if (l31 == 0) {
#pragma unroll
        for (int reg = 0; reg < 16; reg++) {
          int rloc = (reg & 3) + 8 * (reg >> 2) + 4 * h;
          redA[cw][rw * 64 + i * 32 + rloc] = rmax[reg];
        }
      }
    }
    if (!diagb) {
#pragma unroll
      for (int j = 0; j < 2; j++) {
        float m = -3.0e38f;
#pragma unroll
        for (int i = 0; i < 2; i++)
#pragma unroll
          for (int reg = 0; reg < 16; reg++) m = fmaxf(m, acc[i][j][reg]);
        m = fmaxf(m, __shfl_xor(m, 32));
        if (h == 0) redB[rw][cw * 64 + j * 32 + l31] = m;
      }
    }
    __syncthreads();
    if (t < BM) {
      partG[((size_t)(gg * NSTRIP + gb)) * N + r0 + t] = fmaxf(redA[0][t], redA[1][t]);
      if (!diagb)
        partG[((size_t)(gg * NSTRIP + ga)) * N + c0 + t] = fmaxf(redB[0][t], redB[1][t]);
    }
  }
}

// ---------------- per-row combine of partials -> atomic scalar ----------------
__global__ __launch_bounds__(256) void combine_kernel(
    const float* __restrict__ diag,
    const float* __restrict__ rowS, const float* __restrict__ colS,
    const float* __restrict__ partG, float* __restrict__ out) {
  const float invT = 25.0f;
  int i = blockIdx.x * 256 + threadIdx.x;

  float s = 0.0f;
  for (int q = 0; q < NSTRIP; q++) s += rowS[(size_t)q * N + i];
  float a12 = logf(s) - diag[i] * invT;

  s = 0.0f;
  for (int o = 0; o < NSTRIP; o++) s += colS[(size_t)o * N + i];
  float a21 = logf(s) - diag[i] * invT;

  float g1 = -3.0e38f, g2 = -3.0e38f;
  for (int o = 0; o < NSTRIP; o++) {
    g1 = fmaxf(g1, partG[(size_t)o * N + i]);
    g2 = fmaxf(g2, partG[(size_t)(NSTRIP + o) * N + i]);
  }
  float k1 = logf(sqrtf(fmaxf(2.0f - 2.0f * g1, 0.0f)) + 1e-9f);
  float k2 = logf(sqrtf(fmaxf(2.0f - 2.0f * g2, 0.0f)) + 1e-9f);

  float c = 0.5f * (a12 + a21) / (float)N - 0.1f * 0.5f * (k1 + k2) / (float)N;
#pragma unroll
  for (int off = 1; off < 64; off <<= 1) c += __shfl_xor(c, off);
  __shared__ float fr[4];
  int wv = threadIdx.x >> 6;
  if ((threadIdx.x & 63) == 0) fr[wv] = c;
  __syncthreads();
  if (threadIdx.x == 0)
    atomicAdd(out, fr[0] + fr[1] + fr[2] + fr[3]); // device-scope, out zeroed by norm_kernel
}

extern "C" void kernel_launch(void* const* d_in, const int* in_sizes, int n_in,
                              void* d_out, int out_size, void* d_ws, size_t ws_size,
                              hipStream_t stream) {
  const float* z1 = (const float*)d_in[0];
  const float* z2 = (const float*)d_in[1];
  char* w = (char*)d_ws;
  unsigned char* q1 = (unsigned char*)w; w += (size_t)N * D;
  unsigned char* q2 = (unsigned char*)w; w += (size_t)N * D;
  float* diag = (float*)w;   w += (size_t)N * sizeof(float);
  float* rowS = (float*)w;   w += (size_t)NSTRIP * N * sizeof(float);
  float* colS = (float*)w;   w += (size_t)NSTRIP * N * sizeof(float);
  float* partG = (float*)w;  w += (size_t)2 * NSTRIP * N * sizeof(float);
  float* out = (float*)d_out;

  norm_kernel<<<N, 256, 0, stream>>>(z1, z2, q1, q2, diag, out);
  sg_kernel<<<SG_BLOCKS, 256, 0, stream>>>(q1, q2, rowS, colS, partG);
  combine_kernel<<<N / 256, 256, 0, stream>>>(diag, rowS, colS, partG, out);
}